// Round 4
// baseline (3211.751 us; speedup 1.0000x reference)
//
#include <hip/hip_runtime.h>
#include <hip/hip_bf16.h>
#include <stdint.h>

#define BATCH 32
#define CIN 128
#define HH 64
#define WW 64
#define MID 256
#define NCLS 65
#define HI 512
#define NWORDS 8   // 512 cols / 64 bits

// ---------------------------------------------------------------------------
// Transpose w1 [m][c][k] -> w1t [c*9+k][m] so conv weight loads coalesce.
// ---------------------------------------------------------------------------
__global__ __launch_bounds__(256) void transpose_w1(
    const float* __restrict__ w1, float* __restrict__ w1t)
{
    const int i = blockIdx.x * 256 + threadIdx.x;   // i = ck*256 + m
    if (i >= MID * CIN * 9) return;
    const int ck = i >> 8;
    const int m  = i & 255;
    w1t[i] = w1[m * (CIN * 9) + ck];
}

// ---------------------------------------------------------------------------
// Conv3x3 accumulate for one mid (this thread) over a 4x4 pixel tile.
// Patch values are BLOCK-UNIFORM loads from x (compiler can scalarize to
// s_load -> SGPRs; worst case same-address vector load via L1). No LDS.
// Accumulation order per acc[p] identical to prior rounds (bit-exact).
// ---------------------------------------------------------------------------
template<bool INTERIOR>
__device__ __forceinline__ void conv_rows(
    const float* __restrict__ xb, const float* __restrict__ wcol,
    int y0, int x0, float acc[16])
{
    for (int c = 0; c < CIN; ++c) {
        const float* xc = xb + c * (HH * WW);
        float wreg[9];
#pragma unroll
        for (int k = 0; k < 9; ++k)
            wreg[k] = wcol[(c * 9 + k) * MID];      // lane-coalesced
        float pr[6][6];                             // wave-uniform values
        if (INTERIOR) {
            const float* xt = xc + (y0 - 1) * WW + (x0 - 1);
#pragma unroll
            for (int r = 0; r < 6; ++r)
#pragma unroll
                for (int cc = 0; cc < 6; ++cc)
                    pr[r][cc] = xt[r * WW + cc];
        } else {
#pragma unroll
            for (int r = 0; r < 6; ++r) {
                const int yy = y0 - 1 + r;
                const int yc = yy < 0 ? 0 : (yy > HH - 1 ? HH - 1 : yy);
#pragma unroll
                for (int cc = 0; cc < 6; ++cc) {
                    const int xx = x0 - 1 + cc;
                    const int xcl = xx < 0 ? 0 : (xx > WW - 1 ? WW - 1 : xx);
                    const float v = xc[yc * WW + xcl];   // clamped (safe) load
                    pr[r][cc] =
                        ((unsigned)yy < HH && (unsigned)xx < WW) ? v : 0.f;
                }
            }
        }
        // patch row r feeds output rows py = r - ky; order (ky,kx) ascending
        // per output == previous rounds' order -> bit-identical sums.
#pragma unroll
        for (int ky = 0; ky < 3; ++ky)
#pragma unroll
            for (int r = 0; r < 6; ++r) {
                const int py = r - ky;
                if (py < 0 || py > 3) continue;
#pragma unroll
                for (int kx = 0; kx < 3; ++kx)
#pragma unroll
                    for (int px = 0; px < 4; ++px)
                        acc[py * 4 + px] = fmaf(pr[r][px + kx],
                                                wreg[ky * 3 + kx],
                                                acc[py * 4 + px]);
            }
    }
}

// ---------------------------------------------------------------------------
// Fused conv3x3+relu -> 1x1 conv -> softmax(65) -> pixel-shuffle -> threshold.
// Block: 256 threads = 256 mids, one 4x4 pixel tile of one image.
// ---------------------------------------------------------------------------
__global__ __launch_bounds__(256) void head_kernel(
    const float* __restrict__ x, const float* __restrict__ w1t,
    const float* __restrict__ b1, const float* __restrict__ w2,
    const float* __restrict__ b2, float* __restrict__ out)
{
    const int b  = blockIdx.z;
    const int y0 = blockIdx.y * 4;
    const int x0 = blockIdx.x * 4;
    const int tid = threadIdx.x;

    __shared__ float hb[MID * 17];   // hidden acts, pad 17 (conflict-free)
    __shared__ float sem[16 * 66];   // [p][o] logits then exps
    __shared__ float rinv[16];

    const float* xb = x + (size_t)b * CIN * HH * WW;
    {
        float acc[16];
        const float bb = b1[tid];
#pragma unroll
        for (int p = 0; p < 16; ++p) acc[p] = bb;
        const bool interior = blockIdx.x >= 1 && blockIdx.x <= 14 &&
                              blockIdx.y >= 1 && blockIdx.y <= 14;
        if (interior) conv_rows<true >(xb, w1t + tid, y0, x0, acc);
        else          conv_rows<false>(xb, w1t + tid, y0, x0, acc);
#pragma unroll
        for (int p = 0; p < 16; ++p) hb[tid * 17 + p] = fmaxf(acc[p], 0.f);
    }
    __syncthreads();

    // ---- 1x1 conv: 65 outputs x 16 pixels, dot over 256 mids ----
    for (int t = tid; t < NCLS * 16; t += 256) {
        const int o = t >> 4, p = t & 15;
        float a = b2[o];
        const float* w2r = w2 + (size_t)o * MID;
#pragma unroll 8
        for (int mm = 0; mm < MID; ++mm)
            a = fmaf(hb[mm * 17 + p], w2r[mm], a);
        sem[p * 66 + o] = a;
    }
    __syncthreads();

    // ---- softmax per pixel: 4 lanes per pixel (quad shuffle reduce) ----
    if (tid < 64) {
        const int p = tid >> 2, q = tid & 3;
        const int o0 = q * 17;
        const int o1 = (o0 + 17 < NCLS) ? o0 + 17 : NCLS;
        float mx = -1e30f;
        for (int o = o0; o < o1; ++o) mx = fmaxf(mx, sem[p * 66 + o]);
        mx = fmaxf(mx, __shfl_xor(mx, 1));
        mx = fmaxf(mx, __shfl_xor(mx, 2));
        float s = 0.f;
        for (int o = o0; o < o1; ++o) {
            float e = __expf(sem[p * 66 + o] - mx);
            sem[p * 66 + o] = e;
            s += e;
        }
        s += __shfl_xor(s, 1);
        s += __shfl_xor(s, 2);
        if (q == 0) rinv[p] = 1.f / s;
    }
    __syncthreads();

    // ---- pixel-shuffle write with conf threshold (classes 0..63) ----
    for (int t = tid; t < 16 * 64; t += 256) {
        const int p = t >> 6, o = t & 63;
        float v = sem[p * 66 + o] * rinv[p];
        if (!(v >= 0.015f)) v = 0.f;
        const int py = p >> 2, px = p & 3;
        const int row = (y0 + py) * 8 + (o >> 3);
        const int col = (x0 + px) * 8 + (o & 7);
        out[((size_t)b * HI + row) * HI + col] = v;
    }
}

// ---------------------------------------------------------------------------
// One NMS iteration, bit-packed masks. Min==nullptr means all-zero mask,
// which makes this exactly the init step (new = maxmask(S)).
//   supp = dilate9x9(Min); s = supp?0:S; new = (s==maxpool9x9(s)) && s>0;
//   Mout = Min | new.
// Tile 64x64 (one uint64 word wide), halo 8 for masks / 4 for scores.
// ---------------------------------------------------------------------------
__global__ __launch_bounds__(256) void nms_iter(
    const float* __restrict__ S, const uint64_t* __restrict__ Min,
    uint64_t* __restrict__ Mout)
{
    const int b = blockIdx.z;
    const int bx = blockIdx.x;           // word index W
    const int ty = blockIdx.y * 64, tx = bx * 64;
    const int tid = threadIdx.x;

    __shared__ uint64_t smw[80 * 3];     // mask rows ty-8.., words W-1..W+1
    __shared__ uint64_t hd[80 * 3];      // horizontal dilate +-4
    __shared__ uint64_t sup[72 * 3];     // vertical OR of 9 -> suppression
    __shared__ __align__(16) float sfl[72 * 76];  // suppressed scores, pad 76
    __shared__ __align__(16) float rm[72 * 64];   // row max

    // phase 1: load mask words (zero OOB / null)
    if (tid < 240) {
        const int i = tid / 3, j = tid % 3;
        const int yy = ty - 8 + i;
        const int wj = bx - 1 + j;
        uint64_t v = 0;
        if (Min && (unsigned)yy < HI && (unsigned)wj < NWORDS)
            v = Min[((size_t)b * HI + yy) * NWORDS + wj];
        smw[tid] = v;
    }
    __syncthreads();
    // phase 2: horizontal dilate +-4 (bit k <- OR of bits k-4..k+4)
    if (tid < 240) {
        const int i = tid / 3, j = tid % 3;
        const uint64_t c = smw[i * 3 + j];
        const uint64_t l = j > 0 ? smw[i * 3 + j - 1] : 0ull;
        const uint64_t r = j < 2 ? smw[i * 3 + j + 1] : 0ull;
        uint64_t d = c;
#pragma unroll
        for (int s = 1; s <= 4; ++s)
            d |= (c >> s) | (r << (64 - s)) | (c << s) | (l >> (64 - s));
        hd[tid] = d;
    }
    __syncthreads();
    // phase 3: vertical OR of 9 rows
    if (tid < 216) {
        const int r = tid / 3, j = tid % 3;
        uint64_t v = 0;
#pragma unroll
        for (int k = 0; k < 9; ++k) v |= hd[(r + k) * 3 + j];
        sup[tid] = v;
    }
    __syncthreads();
    // phase 4: stage suppressed scores (rows ty-4..ty+67, cols tx-4..tx+67)
    const float* Sb = S + (size_t)b * HI * HI;
    for (int k = tid; k < 72 * 18; k += 256) {
        const int r = k / 18, f4 = k % 18;
        const int gy = ty - 4 + r;
        const int gx0 = tx - 4 + f4 * 4;
        float4 v = make_float4(0.f, 0.f, 0.f, 0.f);
        float* pv = (float*)&v;
        if ((unsigned)gy < HI) {
            if (gx0 >= 0 && gx0 + 3 < HI)
                v = *(const float4*)(Sb + (size_t)gy * HI + gx0);
            else {
#pragma unroll
                for (int cc = 0; cc < 4; ++cc)
                    if ((unsigned)(gx0 + cc) < HI)
                        pv[cc] = Sb[(size_t)gy * HI + gx0 + cc];
            }
        }
        const int rel64 = 60 + 4 * f4;            // offset from word W-1 base
        const uint64_t w = sup[r * 3 + (rel64 >> 6)];
        const int b0 = rel64 & 63;                // group never crosses a word
#pragma unroll
        for (int cc = 0; cc < 4; ++cc)
            if ((w >> (b0 + cc)) & 1ull) pv[cc] = 0.f;
        *(float4*)(sfl + r * 76 + f4 * 4) = v;
    }
    __syncthreads();
    // phase 5: horizontal 9-max, 4 outputs per task from 12 values
    for (int k = tid; k < 72 * 16; k += 256) {
        const int r = k / 16, x4 = (k % 16) * 4;
        const float4 a  = *(const float4*)(sfl + r * 76 + x4);
        const float4 bq = *(const float4*)(sfl + r * 76 + x4 + 4);
        const float4 cq = *(const float4*)(sfl + r * 76 + x4 + 8);
        const float v0=a.x,v1=a.y,v2=a.z,v3=a.w;
        const float v4=bq.x,v5=bq.y,v6=bq.z,v7=bq.w;
        const float v8=cq.x,v9=cq.y,v10=cq.z,v11=cq.w;
        const float m4567 = fmaxf(fmaxf(v4,v5), fmaxf(v6,v7));
        const float m23 = fmaxf(v2,v3), m89 = fmaxf(v8,v9);
        const float o0 = fmaxf(fmaxf(fmaxf(v0,v1), m23), fmaxf(m4567, v8));
        const float o1 = fmaxf(fmaxf(v1, m23), fmaxf(m4567, m89));
        const float o2 = fmaxf(fmaxf(m23, m4567), fmaxf(m89, v10));
        const float o3 = fmaxf(fmaxf(v3, m4567), fmaxf(fmaxf(m89, v10), v11));
        *(float4*)(rm + r * 64 + x4) = make_float4(o0,o1,o2,o3);
    }
    __syncthreads();
    // phase 6: vertical 9-max (sliding ring), decide, ballot into word
    {
        const int wv = tid >> 6, lane = tid & 63;
        const int ybase = wv * 16;
        float ring[9];
#pragma unroll
        for (int k = 0; k < 8; ++k) ring[k] = rm[(ybase + k) * 64 + lane];
#pragma unroll
        for (int q = 0; q < 16; ++q) {
            const int y = ybase + q;
            ring[(q + 8) % 9] = rm[(y + 8) * 64 + lane];
            float mv = ring[0];
#pragma unroll
            for (int k = 1; k < 9; ++k) mv = fmaxf(mv, ring[k]);
            const float c = sfl[(y + 4) * 76 + lane + 4];
            const uint64_t oldw = smw[(y + 8) * 3 + 1];
            const bool keep = ((oldw >> lane) & 1ull) || (c == mv && c > 0.f);
            const uint64_t word = __ballot(keep);   // lane i -> bit i
            if (lane == 0)
                Mout[((size_t)b * HI + ty + y) * NWORDS + bx] = word;
        }
    }
}

// ---------------------------------------------------------------------------
// Finalize: out = (Mbit && border) ? S : 0, in place on d_out.
// ---------------------------------------------------------------------------
__global__ __launch_bounds__(256) void finalize_bits(
    float* __restrict__ S, const uint64_t* __restrict__ Mw)
{
    const int i4 = blockIdx.x * 256 + threadIdx.x;      // float4 index
    const size_t base = (size_t)i4 * 4;
    const int x = (int)(base & 511);
    const int y = (int)((base >> 9) & 511);
    const int bb = (int)(base >> 18);
    const uint64_t w = Mw[((size_t)bb * HI + y) * NWORDS + (x >> 6)];
    float4 v = ((const float4*)S)[i4];
    float* pv = (float*)&v;
    const bool rowok = (y >= 4) && (y < HI - 4);
#pragma unroll
    for (int cc = 0; cc < 4; ++cc) {
        const int xx = x + cc;
        const bool keep = rowok && (xx >= 4) && (xx < HI - 4) &&
                          ((w >> (xx & 63)) & 1ull);
        if (!keep) pv[cc] = 0.f;
    }
    ((float4*)S)[i4] = v;
}

extern "C" void kernel_launch(void* const* d_in, const int* in_sizes, int n_in,
                              void* d_out, int out_size, void* d_ws, size_t ws_size,
                              hipStream_t stream) {
    const float* x  = (const float*)d_in[0];
    const float* w1 = (const float*)d_in[1];
    const float* b1 = (const float*)d_in[2];
    const float* w2 = (const float*)d_in[3];
    const float* b2 = (const float*)d_in[4];
    float* out = (float*)d_out;

    // ws: w1t (1.18 MB) | MA (1 MB) | MB (1 MB)  -- total ~4.2 MB
    float* w1t = (float*)d_ws;
    uint64_t* MA = (uint64_t*)((char*)d_ws + (2u << 20));
    uint64_t* MB = MA + (size_t)BATCH * HI * NWORDS;

    transpose_w1<<<(MID * CIN * 9 + 255) / 256, 256, 0, stream>>>(w1, w1t);
    head_kernel<<<dim3(16, 16, BATCH), 256, 0, stream>>>(x, w1t, b1, w2, b2, out);

    dim3 g(NWORDS, 8, BATCH);
    nms_iter<<<g, 256, 0, stream>>>(out, nullptr, MA);   // init (zero mask)
    for (int it = 0; it < 4; ++it) {                     // 8 iterations
        nms_iter<<<g, 256, 0, stream>>>(out, MA, MB);
        nms_iter<<<g, 256, 0, stream>>>(out, MB, MA);
    }
    const int nf4 = BATCH * HI * HI / 4;
    finalize_bits<<<nf4 / 256, 256, 0, stream>>>(out, MA);
}

// Round 5
// 1453.567 us; speedup vs baseline: 2.2096x; 2.2096x over previous
//
#include <hip/hip_runtime.h>
#include <hip/hip_bf16.h>
#include <stdint.h>

#define BATCH 32
#define CIN 128
#define HH 64
#define WW 64
#define MID 256
#define NCLS 65
#define HI 512
#define NWORDS 8   // 512 cols / 64 bits
#define HBS 260    // hb row stride (pad: 260 mod 32 = 4 -> ~2-way, free)

// ---------------------------------------------------------------------------
// Transpose w1 [m][c][k] -> w1t [c*9+k][m] so conv weight loads coalesce.
// ---------------------------------------------------------------------------
__global__ __launch_bounds__(256) void transpose_w1(
    const float* __restrict__ w1, float* __restrict__ w1t)
{
    const int i = blockIdx.x * 256 + threadIdx.x;   // i = ck*256 + m
    if (i >= MID * CIN * 9) return;
    const int ck = i >> 8;
    const int m  = i & 255;
    w1t[i] = w1[m * (CIN * 9) + ck];
}

// ---------------------------------------------------------------------------
// Fused conv3x3+relu -> 1x1 conv -> softmax(65) -> pixel-shuffle -> threshold.
// Block: 256 threads, one 4x4 pixel tile. Conv: thread = mid, patch staged in
// LDS, rows read as 3x ds_read_b64 feeding fmaf directly (no expansion movs).
// 1x1: thread = (pixel, 4-output group), hb transposed [p][m] -> b128 reads.
// All accumulation orders identical to round 3 (bit-exact output).
// ---------------------------------------------------------------------------
__global__ __launch_bounds__(256, 4) void head_kernel(
    const float* __restrict__ x, const float* __restrict__ w1t,
    const float* __restrict__ b1, const float* __restrict__ w2,
    const float* __restrict__ b2, float* __restrict__ out)
{
    const int b  = blockIdx.z;
    const int y0 = blockIdx.y * 4;
    const int x0 = blockIdx.x * 4;
    const int tid = threadIdx.x;

    __shared__ float xp[CIN * 36];      // patch [c][r*6+cc]; reused as sem
    __shared__ float hb[16 * HBS];      // hidden acts [p][m], pad 260
    __shared__ float rinv[16];
    float* const sem = xp;              // [p][o] stride 66; xp dead by then

    // ---- stage input patch (rows y0-1..y0+4, cols x0-1..x0+4, zero pad) ----
    const float* xb = x + (size_t)b * CIN * HH * WW;
    for (int i = tid; i < CIN * 36; i += 256) {
        int c = i / 36, r = i % 36;
        int yy = y0 - 1 + (r / 6), xx = x0 - 1 + (r % 6);
        float v = 0.f;
        if ((unsigned)yy < HH && (unsigned)xx < WW)
            v = xb[(c * HH + yy) * WW + xx];
        xp[i] = v;
    }
    __syncthreads();

    // ---- conv3x3: thread = mid, 16 pixels ----
    {
        float acc[16];
        const float bb = b1[tid];
#pragma unroll
        for (int p = 0; p < 16; ++p) acc[p] = bb;
        const float* wcol = w1t + tid;
        for (int c = 0; c < CIN; ++c) {
            float w[9];
#pragma unroll
            for (int k = 0; k < 9; ++k)
                w[k] = wcol[(c * 9 + k) * MID];     // lane-coalesced
            const float* row = xp + c * 36;
#pragma unroll
            for (int r = 0; r < 6; ++r) {
                const float2 q0 = *(const float2*)(row + r * 6);
                const float2 q1 = *(const float2*)(row + r * 6 + 2);
                const float2 q2 = *(const float2*)(row + r * 6 + 4);
                const float rv[6] = {q0.x, q0.y, q1.x, q1.y, q2.x, q2.y};
#pragma unroll
                for (int ky = 0; ky < 3; ++ky) {
                    const int py = r - ky;
                    if (py < 0 || py > 3) continue;
#pragma unroll
                    for (int kx = 0; kx < 3; ++kx) {
                        const float wv = w[ky * 3 + kx];
#pragma unroll
                        for (int px = 0; px < 4; ++px)
                            acc[py * 4 + px] =
                                fmaf(rv[px + kx], wv, acc[py * 4 + px]);
                    }
                }
            }
        }
#pragma unroll
        for (int p = 0; p < 16; ++p)
            hb[p * HBS + tid] = fmaxf(acc[p], 0.f);
    }
    __syncthreads();

    // ---- 1x1 conv: thread (p = tid&15, g = tid>>4) does o = 4g..4g+3 ----
    {
        const int p = tid & 15, g = tid >> 4;
        float a[4];
#pragma unroll
        for (int j = 0; j < 4; ++j) a[j] = b2[g * 4 + j];
        const float* hrow = hb + p * HBS;
        const float* w2r = w2 + (size_t)(g * 4) * MID;
        for (int mm = 0; mm < MID; mm += 4) {
            const float4 h4 = *(const float4*)(hrow + mm);
#pragma unroll
            for (int j = 0; j < 4; ++j) {
                const float4 w4 = *(const float4*)(w2r + j * MID + mm);
                a[j] = fmaf(h4.x, w4.x, a[j]);
                a[j] = fmaf(h4.y, w4.y, a[j]);
                a[j] = fmaf(h4.z, w4.z, a[j]);
                a[j] = fmaf(h4.w, w4.w, a[j]);
            }
        }
        __syncthreads();                 // xp reads done; safe to write sem
#pragma unroll
        for (int j = 0; j < 4; ++j) sem[p * 66 + g * 4 + j] = a[j];
        // dust class o=64: 16 threads
        if (tid < 16) {
            float ad = b2[64];
            const float* wd = w2 + (size_t)64 * MID;
            const float* hr = hb + tid * HBS;
            for (int mm = 0; mm < MID; mm += 4) {
                const float4 h4 = *(const float4*)(hr + mm);
                const float4 w4 = *(const float4*)(wd + mm);
                ad = fmaf(h4.x, w4.x, ad);
                ad = fmaf(h4.y, w4.y, ad);
                ad = fmaf(h4.z, w4.z, ad);
                ad = fmaf(h4.w, w4.w, ad);
            }
            sem[tid * 66 + 64] = ad;
        }
    }
    __syncthreads();

    // ---- softmax per pixel: 4 lanes per pixel (quad shuffle reduce) ----
    if (tid < 64) {
        const int p = tid >> 2, q = tid & 3;
        const int o0 = q * 17;
        const int o1 = (o0 + 17 < NCLS) ? o0 + 17 : NCLS;
        float mx = -1e30f;
        for (int o = o0; o < o1; ++o) mx = fmaxf(mx, sem[p * 66 + o]);
        mx = fmaxf(mx, __shfl_xor(mx, 1));
        mx = fmaxf(mx, __shfl_xor(mx, 2));
        float s = 0.f;
        for (int o = o0; o < o1; ++o) {
            float e = __expf(sem[p * 66 + o] - mx);
            sem[p * 66 + o] = e;
            s += e;
        }
        s += __shfl_xor(s, 1);
        s += __shfl_xor(s, 2);
        if (q == 0) rinv[p] = 1.f / s;
    }
    __syncthreads();

    // ---- pixel-shuffle write with conf threshold (classes 0..63) ----
    for (int t = tid; t < 16 * 64; t += 256) {
        const int p = t >> 6, o = t & 63;
        float v = sem[p * 66 + o] * rinv[p];
        if (!(v >= 0.015f)) v = 0.f;
        const int py = p >> 2, px = p & 3;
        const int row = (y0 + py) * 8 + (o >> 3);
        const int col = (x0 + px) * 8 + (o & 7);
        out[((size_t)b * HI + row) * HI + col] = v;
    }
}

// ---------------------------------------------------------------------------
// One NMS iteration, bit-packed masks. Min==nullptr => zero mask => init.
//   supp = dilate9x9(Min); s = supp?0:S; new = (s==maxpool9x9(s)) && s>0;
//   Mout = Min | new.   Tile 64x64 (one uint64 word wide).
// ---------------------------------------------------------------------------
__global__ __launch_bounds__(256) void nms_iter(
    const float* __restrict__ S, const uint64_t* __restrict__ Min,
    uint64_t* __restrict__ Mout)
{
    const int b = blockIdx.z;
    const int bx = blockIdx.x;           // word index W
    const int ty = blockIdx.y * 64, tx = bx * 64;
    const int tid = threadIdx.x;

    __shared__ uint64_t smw[80 * 3];     // mask rows ty-8.., words W-1..W+1
    __shared__ uint64_t hd[80 * 3];      // horizontal dilate +-4
    __shared__ uint64_t sup[72 * 3];     // vertical OR of 9
    __shared__ __align__(16) float sfl[72 * 76];  // suppressed scores
    __shared__ __align__(16) float rm[72 * 64];   // row max

    if (tid < 240) {
        const int i = tid / 3, j = tid % 3;
        const int yy = ty - 8 + i;
        const int wj = bx - 1 + j;
        uint64_t v = 0;
        if (Min && (unsigned)yy < HI && (unsigned)wj < NWORDS)
            v = Min[((size_t)b * HI + yy) * NWORDS + wj];
        smw[tid] = v;
    }
    __syncthreads();
    if (tid < 240) {
        const int i = tid / 3, j = tid % 3;
        const uint64_t c = smw[i * 3 + j];
        const uint64_t l = j > 0 ? smw[i * 3 + j - 1] : 0ull;
        const uint64_t r = j < 2 ? smw[i * 3 + j + 1] : 0ull;
        uint64_t d = c;
#pragma unroll
        for (int s = 1; s <= 4; ++s)
            d |= (c >> s) | (r << (64 - s)) | (c << s) | (l >> (64 - s));
        hd[tid] = d;
    }
    __syncthreads();
    if (tid < 216) {
        const int r = tid / 3, j = tid % 3;
        uint64_t v = 0;
#pragma unroll
        for (int k = 0; k < 9; ++k) v |= hd[(r + k) * 3 + j];
        sup[tid] = v;
    }
    __syncthreads();
    const float* Sb = S + (size_t)b * HI * HI;
    for (int k = tid; k < 72 * 18; k += 256) {
        const int r = k / 18, f4 = k % 18;
        const int gy = ty - 4 + r;
        const int gx0 = tx - 4 + f4 * 4;
        float4 v = make_float4(0.f, 0.f, 0.f, 0.f);
        float* pv = (float*)&v;
        if ((unsigned)gy < HI) {
            if (gx0 >= 0 && gx0 + 3 < HI)
                v = *(const float4*)(Sb + (size_t)gy * HI + gx0);
            else {
#pragma unroll
                for (int cc = 0; cc < 4; ++cc)
                    if ((unsigned)(gx0 + cc) < HI)
                        pv[cc] = Sb[(size_t)gy * HI + gx0 + cc];
            }
        }
        const int rel64 = 60 + 4 * f4;
        const uint64_t w = sup[r * 3 + (rel64 >> 6)];
        const int b0 = rel64 & 63;
#pragma unroll
        for (int cc = 0; cc < 4; ++cc)
            if ((w >> (b0 + cc)) & 1ull) pv[cc] = 0.f;
        *(float4*)(sfl + r * 76 + f4 * 4) = v;
    }
    __syncthreads();
    for (int k = tid; k < 72 * 16; k += 256) {
        const int r = k / 16, x4 = (k % 16) * 4;
        const float4 a  = *(const float4*)(sfl + r * 76 + x4);
        const float4 bq = *(const float4*)(sfl + r * 76 + x4 + 4);
        const float4 cq = *(const float4*)(sfl + r * 76 + x4 + 8);
        const float v0=a.x,v1=a.y,v2=a.z,v3=a.w;
        const float v4=bq.x,v5=bq.y,v6=bq.z,v7=bq.w;
        const float v8=cq.x,v9=cq.y,v10=cq.z,v11=cq.w;
        const float m4567 = fmaxf(fmaxf(v4,v5), fmaxf(v6,v7));
        const float m23 = fmaxf(v2,v3), m89 = fmaxf(v8,v9);
        const float o0 = fmaxf(fmaxf(fmaxf(v0,v1), m23), fmaxf(m4567, v8));
        const float o1 = fmaxf(fmaxf(v1, m23), fmaxf(m4567, m89));
        const float o2 = fmaxf(fmaxf(m23, m4567), fmaxf(m89, v10));
        const float o3 = fmaxf(fmaxf(v3, m4567), fmaxf(fmaxf(m89, v10), v11));
        *(float4*)(rm + r * 64 + x4) = make_float4(o0,o1,o2,o3);
    }
    __syncthreads();
    {
        const int wv = tid >> 6, lane = tid & 63;
        const int ybase = wv * 16;
        float ring[9];
#pragma unroll
        for (int k = 0; k < 8; ++k) ring[k] = rm[(ybase + k) * 64 + lane];
#pragma unroll
        for (int q = 0; q < 16; ++q) {
            const int y = ybase + q;
            ring[(q + 8) % 9] = rm[(y + 8) * 64 + lane];
            float mv = ring[0];
#pragma unroll
            for (int k = 1; k < 9; ++k) mv = fmaxf(mv, ring[k]);
            const float c = sfl[(y + 4) * 76 + lane + 4];
            const uint64_t oldw = smw[(y + 8) * 3 + 1];
            const bool keep = ((oldw >> lane) & 1ull) || (c == mv && c > 0.f);
            const uint64_t word = __ballot(keep);
            if (lane == 0)
                Mout[((size_t)b * HI + ty + y) * NWORDS + bx] = word;
        }
    }
}

// ---------------------------------------------------------------------------
// Finalize: out = (Mbit && border) ? S : 0, in place on d_out.
// ---------------------------------------------------------------------------
__global__ __launch_bounds__(256) void finalize_bits(
    float* __restrict__ S, const uint64_t* __restrict__ Mw)
{
    const int i4 = blockIdx.x * 256 + threadIdx.x;
    const size_t base = (size_t)i4 * 4;
    const int x = (int)(base & 511);
    const int y = (int)((base >> 9) & 511);
    const int bb = (int)(base >> 18);
    const uint64_t w = Mw[((size_t)bb * HI + y) * NWORDS + (x >> 6)];
    float4 v = ((const float4*)S)[i4];
    float* pv = (float*)&v;
    const bool rowok = (y >= 4) && (y < HI - 4);
#pragma unroll
    for (int cc = 0; cc < 4; ++cc) {
        const int xx = x + cc;
        const bool keep = rowok && (xx >= 4) && (xx < HI - 4) &&
                          ((w >> (xx & 63)) & 1ull);
        if (!keep) pv[cc] = 0.f;
    }
    ((float4*)S)[i4] = v;
}

extern "C" void kernel_launch(void* const* d_in, const int* in_sizes, int n_in,
                              void* d_out, int out_size, void* d_ws, size_t ws_size,
                              hipStream_t stream) {
    const float* x  = (const float*)d_in[0];
    const float* w1 = (const float*)d_in[1];
    const float* b1 = (const float*)d_in[2];
    const float* w2 = (const float*)d_in[3];
    const float* b2 = (const float*)d_in[4];
    float* out = (float*)d_out;

    // ws: w1t (1.18 MB) | MA (1 MB) | MB (1 MB)
    float* w1t = (float*)d_ws;
    uint64_t* MA = (uint64_t*)((char*)d_ws + (2u << 20));
    uint64_t* MB = MA + (size_t)BATCH * HI * NWORDS;

    transpose_w1<<<(MID * CIN * 9 + 255) / 256, 256, 0, stream>>>(w1, w1t);
    head_kernel<<<dim3(16, 16, BATCH), 256, 0, stream>>>(x, w1t, b1, w2, b2, out);

    dim3 g(NWORDS, 8, BATCH);
    nms_iter<<<g, 256, 0, stream>>>(out, nullptr, MA);   // init (zero mask)
    for (int it = 0; it < 4; ++it) {                     // 8 iterations
        nms_iter<<<g, 256, 0, stream>>>(out, MA, MB);
        nms_iter<<<g, 256, 0, stream>>>(out, MB, MA);
    }
    const int nf4 = BATCH * HI * HI / 4;
    finalize_bits<<<nf4 / 256, 256, 0, stream>>>(out, MA);
}